// Round 6
// baseline (132.633 us; speedup 1.0000x reference)
//
#include <hip/hip_runtime.h>

#define N_NODES 100000
#define N_EDGES 1250000
#define D_FEAT  64

#define NPB     392                          // nodes per coarse bin
#define NBINS   256                          // k1 bin count
#define BCAP    6144                         // entries per bin (mean 4900, +17.8 sigma)
#define HALF    196                          // nodes per k23 block (half bin)
#define HCAP    3328                         // per-half sorted-list cap (mean 2450, +17.7 sigma)
#define K23B    (NBINS * 2)                  // 512 blocks = exactly 2 per CU
#define EPB     5120                         // edges per k1 block
#define EPT     10                           // edges per thread (512 thr)
#define K1B     ((N_EDGES + EPB - 1) / EPB)  // 245 -> <= 1 block per CU
#define OVF_CAP 32768

// =============== k1: LDS-staged counting-sort binning (245 blocks) ===============
// Block-local counting sort by bin (256 bins of 392 nodes), then run-coalesced
// dense writes of packed (dloc<<17 | src) into per-bin slabs. Mean run = 20
// words (80B). Global cursor atomics: one per bin per block from CONSECUTIVE
// lanes (never per-edge random-lane atomics -- round-3: those cost 900us).
__global__ __launch_bounds__(512) void k1_bin_kernel(
        const int* __restrict__ idxi, const int* __restrict__ idxj,
        int* __restrict__ gcursor, int* __restrict__ ovfcnt,
        int* __restrict__ ovf, int* __restrict__ binbuf) {
    __shared__ int hist[NBINS];
    __shared__ int runstart[NBINS];
    __shared__ int gbase[NBINS];
    __shared__ int cur[NBINS];
    __shared__ int staged[EPB];               // 20 KB
    __shared__ unsigned char sbin[EPB];       // 5 KB
    int t = threadIdx.x;
    if (t < NBINS) hist[t] = 0;
    __syncthreads();

    int base = blockIdx.x * EPB;
    int n = N_EDGES - base; if (n > EPB) n = EPB;

    int d[EPT], s[EPT], bn[EPT];
#pragma unroll
    for (int j = 0; j < EPT; ++j) {           // issue all loads first (MLP)
        int i = t + j * 512;
        if (i < n) { d[j] = idxi[base + i]; s[j] = idxj[base + i]; }
        else       { d[j] = -1; s[j] = 0; }
    }
#pragma unroll
    for (int j = 0; j < EPT; ++j) {
        bn[j] = (d[j] >= 0) ? (d[j] / NPB) : -1;   // magic-mul division
        if (bn[j] >= 0) atomicAdd(&hist[bn[j]], 1);
    }
    __syncthreads();

    // single-wave exclusive scan over 256 bins, 4 bins/lane, no barriers inside
    if (t < 64) {
        int b0 = t * 4;
        int h0 = hist[b0], h1 = hist[b0 + 1], h2 = hist[b0 + 2], h3 = hist[b0 + 3];
        int s01 = h0 + h1;
        int sum = s01 + h2 + h3;
        int inc = sum;
#pragma unroll
        for (int off = 1; off < 64; off <<= 1) {
            int u = __shfl_up(inc, off, 64);
            if (t >= off) inc += u;
        }
        int ex = inc - sum;
        runstart[b0]     = ex;
        runstart[b0 + 1] = ex + h0;
        runstart[b0 + 2] = ex + s01;
        runstart[b0 + 3] = ex + s01 + h2;
    }
    __syncthreads();

    if (t < NBINS) {
        int h = hist[t];
        gbase[t] = h ? atomicAdd(&gcursor[t], h) : 0;   // consecutive lanes
        cur[t] = 0;
    }
    __syncthreads();

#pragma unroll
    for (int j = 0; j < EPT; ++j) {
        if (bn[j] >= 0) {
            int idx = runstart[bn[j]] + atomicAdd(&cur[bn[j]], 1);
            staged[idx] = ((d[j] - bn[j] * NPB) << 17) | s[j];
            sbin[idx] = (unsigned char)bn[j];
        }
    }
    __syncthreads();

    for (int i = t; i < n; i += 512) {
        int b = sbin[i];
        int p = staged[i];
        int tgt = gbase[b] + (i - runstart[b]);
        if (tgt < BCAP) {
            binbuf[b * BCAP + tgt] = p;
        } else {
            int op = atomicAdd(ovfcnt, 1);
            if (op < OVF_CAP) { ovf[2 * op] = b * NPB + (p >> 17); ovf[2 * op + 1] = p & 0x1FFFF; }
        }
    }
}

// =============== k23: half-bin sort + deep-MLP gather (512 blocks, 2/CU) ===============
// Each 1024-thread block owns HALF of a coarse bin (196 nodes): reads the full
// bin buffer, counting-sorts only its own half's entries into a 13.3KB LDS
// list (wave-0 shuffle scan), then gathers with an 8-deep row unroll: 8
// independent 256B row-loads in flight per wave, no shuffles, direct coalesced
// float4 stores. 2 blocks/CU (launch_bounds VGPR<=64) doubles resident waves;
// round-5 showed per-CU throughput scales with resident waves (latency-bound).
__global__ __launch_bounds__(1024, 8) void k23_fused_kernel(
        const float* __restrict__ x, const int* __restrict__ gcursor,
        const int* __restrict__ binbuf, const int* __restrict__ ovfcnt,
        const int* __restrict__ ovf, float* __restrict__ out) {
    __shared__ int cnt[HALF];
    __shared__ int excl[HALF];
    __shared__ int cur[HALF];
    __shared__ int srt[HCAP];                 // 13.3 KB sorted source list
    int blk = blockIdx.x;
    int bin = blk >> 1;
    int hi  = blk & 1;
    int lobase = hi * HALF;
    int t = threadIdx.x;
    if (t < HALF) cnt[t] = 0;
    __syncthreads();

    int n = gcursor[bin];
    if (n > BCAP) n = BCAP;
    const int* src = binbuf + (size_t)bin * BCAP;

    int p[6];
#pragma unroll
    for (int j = 0; j < 6; ++j) {             // issue all loads first (MLP)
        int i = t + j * 1024;
        p[j] = (i < n) ? src[i] : -1;
    }
#pragma unroll
    for (int j = 0; j < 6; ++j) {
        if (p[j] >= 0) {
            int loc = (p[j] >> 17) - lobase;
            if ((unsigned)loc < HALF) atomicAdd(&cnt[loc], 1);
            else p[j] = -1;                   // other half's entry
        }
    }
    __syncthreads();

    // single-wave exclusive scan over 196 counters, 4/lane, no barriers inside
    if (t < 64) {
        int h[4];
        int sum = 0;
#pragma unroll
        for (int q = 0; q < 4; ++q) {
            int b = t * 4 + q;
            h[q] = (b < HALF) ? cnt[b] : 0;
            sum += h[q];
        }
        int inc = sum;
#pragma unroll
        for (int off = 1; off < 64; off <<= 1) {
            int u = __shfl_up(inc, off, 64);
            if (t >= off) inc += u;
        }
        int ex = inc - sum;
#pragma unroll
        for (int q = 0; q < 4; ++q) {
            int b = t * 4 + q;
            if (b < HALF) { excl[b] = ex; cur[b] = 0; }
            ex += h[q];
        }
    }
    __syncthreads();

#pragma unroll
    for (int j = 0; j < 6; ++j) {
        if (p[j] >= 0) {
            int loc = (p[j] >> 17) - lobase;
            int pos = excl[loc] + atomicAdd(&cur[loc], 1);
            if (pos < HCAP) srt[pos] = p[j] & 0x1FFFF;   // +17.7 sigma guard
        }
    }
    __syncthreads();

    // gather: 64 sub-groups of 16 lanes; sub-group sg -> nodes sg, sg+64, ...
    int sg = t >> 4, c4 = t & 15;
    const float4* xp = (const float4*)x;
#pragma unroll
    for (int i2 = 0; i2 < 4; ++i2) {
        int dl = sg + (i2 << 6);
        if (dl >= HALF) break;
        int node = bin * NPB + lobase + dl;
        int k = excl[dl];
        int end = k + cnt[dl];
        if (end > HCAP) end = HCAP;
        float4 acc = make_float4(0.f, 0.f, 0.f, 0.f);
        for (; k + 8 <= end; k += 8) {        // 8 rows in flight
            int a0 = srt[k],     a1 = srt[k + 1], a2 = srt[k + 2], a3 = srt[k + 3];
            int a4 = srt[k + 4], a5 = srt[k + 5], a6 = srt[k + 6], a7 = srt[k + 7];
            float4 v0 = xp[a0 * 16 + c4];
            float4 v1 = xp[a1 * 16 + c4];
            float4 v2 = xp[a2 * 16 + c4];
            float4 v3 = xp[a3 * 16 + c4];
            float4 v4 = xp[a4 * 16 + c4];
            float4 v5 = xp[a5 * 16 + c4];
            float4 v6 = xp[a6 * 16 + c4];
            float4 v7 = xp[a7 * 16 + c4];
            acc.x += ((v0.x + v1.x) + (v2.x + v3.x)) + ((v4.x + v5.x) + (v6.x + v7.x));
            acc.y += ((v0.y + v1.y) + (v2.y + v3.y)) + ((v4.y + v5.y) + (v6.y + v7.y));
            acc.z += ((v0.z + v1.z) + (v2.z + v3.z)) + ((v4.z + v5.z) + (v6.z + v7.z));
            acc.w += ((v0.w + v1.w) + (v2.w + v3.w)) + ((v4.w + v5.w) + (v6.w + v7.w));
        }
        if (k + 4 <= end) {
            int a0 = srt[k], a1 = srt[k + 1], a2 = srt[k + 2], a3 = srt[k + 3];
            float4 v0 = xp[a0 * 16 + c4];
            float4 v1 = xp[a1 * 16 + c4];
            float4 v2 = xp[a2 * 16 + c4];
            float4 v3 = xp[a3 * 16 + c4];
            acc.x += (v0.x + v1.x) + (v2.x + v3.x);
            acc.y += (v0.y + v1.y) + (v2.y + v3.y);
            acc.z += (v0.z + v1.z) + (v2.z + v3.z);
            acc.w += (v0.w + v1.w) + (v2.w + v3.w);
            k += 4;
        }
        for (; k < end; ++k) {
            float4 v0 = xp[srt[k] * 16 + c4];
            acc.x += v0.x; acc.y += v0.y; acc.z += v0.z; acc.w += v0.w;
        }
        if (node < N_NODES)
            ((float4*)out)[(size_t)node * 16 + c4] = acc;
    }

    // folded overflow fixup: owner half-block adds any of ITS k1-overflow edges
    // on top of its own just-written rows (ovf is complete before k23 starts).
    __syncthreads();
    int novf = *ovfcnt;
    if (novf > 0) {
        __threadfence();
        if (novf > OVF_CAP) novf = OVF_CAP;
        int lo = bin * NPB + lobase;
        for (int e = t; e < novf; e += 1024) {
            int dnode = ovf[2 * e];
            if ((unsigned)(dnode - lo) < HALF && dnode < N_NODES) {
                int snode = ovf[2 * e + 1];
                const float* vsrc = x + (size_t)snode * D_FEAT;
                float* o = out + (size_t)dnode * D_FEAT;
                for (int f = 0; f < D_FEAT; ++f) atomicAdd(o + f, vsrc[f]);
            }
        }
    }
}

// ====================== fallback: atomic scatter-add ======================

__global__ __launch_bounds__(256) void zero_f4_kernel(float* __restrict__ out, int n4) {
    int i = blockIdx.x * blockDim.x + threadIdx.x;
    if (i < n4) ((float4*)out)[i] = make_float4(0.f, 0.f, 0.f, 0.f);
}

__global__ __launch_bounds__(256) void scatter_add_kernel(const float* __restrict__ x,
                                                          const int* __restrict__ idxi,
                                                          const int* __restrict__ idxj,
                                                          float* __restrict__ out) {
    int t = blockIdx.x * blockDim.x + threadIdx.x;
    int e = t >> 4;
    if (e >= N_EDGES) return;
    int fo = (t & 15) << 2;
    int dst = idxi[e];
    int src = idxj[e];
    const float4 v = *(const float4*)(x + (size_t)src * D_FEAT + fo);
    float* o = out + (size_t)dst * D_FEAT + fo;
    atomicAdd(o + 0, v.x);
    atomicAdd(o + 1, v.y);
    atomicAdd(o + 2, v.z);
    atomicAdd(o + 3, v.w);
}

extern "C" void kernel_launch(void* const* d_in, const int* in_sizes, int n_in,
                              void* d_out, int out_size, void* d_ws, size_t ws_size,
                              hipStream_t stream) {
    const float* x  = (const float*)d_in[0];
    const int*   ei = (const int*)d_in[1];   // flat (2, N_EDGES)
    const int*   idxi = ei;                  // row 0: destinations
    const int*   idxj = ei + N_EDGES;        // row 1: sources
    float* out = (float*)d_out;

    // --- primary: counting-sort binning + half-bin sort/gather/fixup ---
    // ws (ints): gcursor[256] | ovfcnt+pad[16] | ovf[2*OVF_CAP] | binbuf[NBINS*BCAP]
    {
        size_t need = (256 + 16 + 2 * (size_t)OVF_CAP +
                       (size_t)NBINS * BCAP) * sizeof(int);
        if (ws_size >= need) {
            int* gcursor = (int*)d_ws;
            int* ovfcnt  = gcursor + 256;
            int* ovf     = ovfcnt + 16;
            int* binbuf  = ovf + 2 * OVF_CAP;

            hipMemsetAsync(gcursor, 0, (256 + 16) * sizeof(int), stream);
            k1_bin_kernel<<<K1B, 512, 0, stream>>>(idxi, idxj, gcursor, ovfcnt, ovf, binbuf);
            k23_fused_kernel<<<K23B, 1024, 0, stream>>>(x, gcursor, binbuf, ovfcnt, ovf, out);
            return;
        }
    }

    // --- fallback: atomic scatter-add ---
    int n4 = (N_NODES * D_FEAT) / 4;
    zero_f4_kernel<<<(n4 + 255) / 256, 256, 0, stream>>>(out, n4);
    long long total_threads = (long long)N_EDGES * 16;
    scatter_add_kernel<<<(int)((total_threads + 255) / 256), 256, 0, stream>>>(x, idxi, idxj, out);
}